// Round 6
// baseline (106.206 us; speedup 1.0000x reference)
//
#include <hip/hip_runtime.h>

// Chamfer loss: B=32, N=M=2048, D=3.
// loss[b] = 0.5 * ( sum_n ma[n]*min_m d2(a_n,b_m) + sum_m mb[m]*min_n d2(b_m,a_n) )
// masked pairs -> BIG^2 = 1e16 (exact in fp32: a2 < ulp(1e16)).
//
// R11: MEASUREMENT ROUND. The main kernel has never appeared in top-5
// (poison fills at ~40us occupy every slot), so 5 rounds of structural
// changes ran blind: R8 (RWx2), R10 (chunk batching) flat; model says
// ~10-12us, budget arithmetic says ~28us. This version doubles the main
// kernel via an internal repeat (r=0 -> real partials, r=1 -> scratch,
// asm memory clobber between so LDS reads can't be CSE'd) to surface it
// in top-5 WITH counters (VGPR/Occupancy/VALUBusy/FETCH/conflicts).
// Piggybacked real improvement: scalar row accumulator + min3 fold
// (fminf(fminf(d.x,d.y),acc) -> v_min3_f32), 5->4 VALU instr/row/tile;
// fmin is exactly associative -> bitwise-identical, absmax 0.0.
#define B_    32
#define N_    2048
#define M_    2048
#define RW_   8        // rows per wave
#define GX_   32       // n-chunks per (b,dir): 2048 / (8 waves * 8 rows)
#define REP_  2        // probe repeats (r=0 real, r=1 scratch)
#define BIG2  1.0e16f

typedef float v2f __attribute__((ext_vector_type(2)));

__device__ __forceinline__ v2f v2_fma(v2f a, v2f b, v2f c) {
#if __has_builtin(__builtin_elementwise_fma)
    return __builtin_elementwise_fma(a, b, c);
#else
    v2f r; r.x = fmaf(a.x, b.x, c.x); r.y = fmaf(a.y, b.y, c.y); return r;
#endif
}
__device__ __forceinline__ v2f v2_splat(float s) { return (v2f){ s, s }; }

union F4V2 { float4 f4; struct { v2f lo, hi; } v; };

// Main: grid (GX_, B_, 2), 512 threads (8 waves). Wave wv owns rows
// [bx*64 + wv*8, +8) (row constants via wave-uniform s_loads). Inner side
// staged ONCE in LDS as point-PAIR SoA:
//   sqA[p] = {-2x_{2p}, -2x_{2p+1}, -2y_{2p}, -2y_{2p+1}}
//   sqB[p] = {-2z_{2p}, -2z_{2p+1},  w_{2p},   w_{2p+1}}   (w = mask?|p|^2:1e16)
// Tile = 64 lanes x 2 points = 128 points; per tile per row:
// 3 pk_fma + 1 min3 (d.x, d.y, scalar acc).
__global__ __launch_bounds__(512) void chamfer_main(
    const int* __restrict__ o_w, const float* __restrict__ o_pts,
    const int* __restrict__ t_w, const float* __restrict__ t_pts,
    float* __restrict__ partials)
{
    const int dir  = blockIdx.z;
    const int b    = blockIdx.y;
    const int tid  = threadIdx.x;
    const int lane = tid & 63;
    const int wv   = tid >> 6;
    const int row0 = blockIdx.x * (8 * RW_) + wv * RW_;

    const int*   wa; const float* pa;   // outer (row) side
    const int*   wb; const float* pb;   // inner (streamed) side
    if (dir == 0) { wa = o_w; pa = o_pts; wb = t_w; pb = t_pts; }
    else          { wa = t_w; pa = t_pts; wb = o_w; pb = o_pts; }

    __shared__ float4 sqA[M_ / 2];      // 16 KB
    __shared__ float4 sqB[M_ / 2];      // 16 KB
    __shared__ float  wsum[8];

    // ---- Stage inner slice ONCE: 512 threads x 2 pair-slots, coalesced float2.
    {
        const float2* src2 = (const float2*)(pb + (size_t)b * M_ * 3);
        const int2*   wb2  = (const int2*)(wb + (size_t)b * M_);
        #pragma unroll
        for (int k = 0; k < 2; ++k) {
            int p = tid + k * 512;                     // pair index 0..1023
            float2 u0 = src2[p * 3 + 0];
            float2 u1 = src2[p * 3 + 1];
            float2 u2 = src2[p * 3 + 2];
            int2   mm = wb2[p];
            float x0 = u0.x, y0 = u0.y, z0 = u1.x;
            float x1 = u1.y, y1 = u2.x, z1 = u2.y;
            float n20 = fmaf(x0, x0, fmaf(y0, y0, z0 * z0));
            float n21 = fmaf(x1, x1, fmaf(y1, y1, z1 * z1));
            sqA[p] = make_float4(-2.f * x0, -2.f * x1, -2.f * y0, -2.f * y1);
            sqB[p] = make_float4(-2.f * z0, -2.f * z1,
                                 mm.x ? n20 : BIG2, mm.y ? n21 : BIG2);
        }
    }

    // ---- Row constants (wave-uniform base -> s_loads).
    int base  = __builtin_amdgcn_readfirstlane((b * N_ + row0) * 3);
    int mbase = __builtin_amdgcn_readfirstlane(b * N_ + row0);
    const float* rp = pa + base;
    const int*   wp = wa + mbase;
    float rx[RW_], ry[RW_], rz[RW_];
    #pragma unroll
    for (int r = 0; r < RW_; ++r) {
        rx[r] = rp[3 * r + 0];
        ry[r] = rp[3 * r + 1];
        rz[r] = rp[3 * r + 2];
    }
    __syncthreads();

    // ---- Probe repeat: rep=0 writes real partials, rep=1 writes scratch.
    for (int rep = 0; rep < REP_; ++rep) {
        // Memory clobber: forbid CSE of LDS reads across repeats so the
        // probe repeat re-executes the full chain.
        asm volatile("" ::: "memory");

        float acc[RW_];
        #pragma unroll
        for (int r = 0; r < RW_; ++r) acc[r] = 3.4e38f;

        // Inner loop: 16 tiles of 128 points, 1-deep LDS prefetch.
        F4V2 qa, qb, na, nb;
        qa.f4 = sqA[lane];
        qb.f4 = sqB[lane];
        #pragma unroll 4
        for (int t = 0; t < M_ / 128; ++t) {
            if (t + 1 < M_ / 128) {
                na.f4 = sqA[(t + 1) * 64 + lane];
                nb.f4 = sqB[(t + 1) * 64 + lane];
            }
            v2f xs = qa.v.lo, ys = qa.v.hi, zs = qb.v.lo, ws = qb.v.hi;
            #pragma unroll
            for (int r = 0; r < RW_; ++r) {
                v2f d = v2_fma(v2_splat(rx[r]), xs,
                        v2_fma(v2_splat(ry[r]), ys,
                        v2_fma(v2_splat(rz[r]), zs, ws)));
                acc[r] = fminf(fminf(d.x, d.y), acc[r]);   // v_min3_f32
            }
            qa = na; qb = nb;
        }

        // Cross-lane min per row, epilogue, block reduce, one store.
        float sum = 0.0f;
        #pragma unroll
        for (int r = 0; r < RW_; ++r) {
            float m = acc[r];
            #pragma unroll
            for (int off = 32; off; off >>= 1)
                m = fminf(m, __shfl_xor(m, off, 64));
            float a2 = fmaf(rx[r], rx[r], fmaf(ry[r], ry[r], rz[r] * rz[r]));
            float d2 = fmaxf(a2 + m, 0.0f);
            sum += (wp[r] != 0) ? d2 : 0.0f;
        }
        if (lane == 0) wsum[wv] = sum;
        __syncthreads();
        if (tid == 0) {
            float s = 0.f;
            #pragma unroll
            for (int i = 0; i < 8; ++i) s += wsum[i];
            partials[(size_t)rep * (B_ * 2 * GX_)
                     + ((size_t)b * 2 + dir) * GX_ + blockIdx.x] = s;
        }
        __syncthreads();   // wsum reusable next repeat
    }
}

// Finish: one block, 256 threads. Thread t: b = t>>3, k = t&7 sums 8 of the
// 64 partials for batch b, then 3-step shfl reduce within the 8-lane group.
// Reads only the rep=0 region. (R5 verbatim.)
__global__ __launch_bounds__(256) void chamfer_finish(
    const float* __restrict__ partials, float* __restrict__ loss)
{
    int t = threadIdx.x;
    int b = t >> 3, k = t & 7;
    const float4* p4 = (const float4*)(partials + b * (2 * GX_) + k * 8);
    float4 u = p4[0], v = p4[1];
    float s = ((u.x + u.y) + (u.z + u.w)) + ((v.x + v.y) + (v.z + v.w));
    #pragma unroll
    for (int off = 4; off; off >>= 1) s += __shfl_xor(s, off, 64);
    if (k == 0) loss[b] = 0.5f * s;
}

// ---------- Fallback (ws too small): prep-on-the-fly + atomics ----------
__global__ void chamfer_zero(float* __restrict__ loss)
{
    if (threadIdx.x < B_) loss[threadIdx.x] = 0.0f;
}

__global__ __launch_bounds__(256) void chamfer_nolds(
    const int* __restrict__ o_w, const float* __restrict__ o_pts,
    const int* __restrict__ t_w, const float* __restrict__ t_pts,
    float* __restrict__ loss)
{
    const int dir  = blockIdx.z;
    const int b    = blockIdx.y;
    const int lane = threadIdx.x & 63;
    const int wv   = threadIdx.x >> 6;
    const int row0 = (blockIdx.x * 4 + wv) * 16;

    const int*   __restrict__ wa = (dir == 0) ? o_w   : t_w;
    const float* __restrict__ pa = (dir == 0) ? o_pts : t_pts;
    const int*   __restrict__ wb = (dir == 0) ? t_w   : o_w;
    const float* __restrict__ pb = (dir == 0) ? t_pts : o_pts;

    int base = __builtin_amdgcn_readfirstlane((b * N_ + row0) * 3);
    const float* rp = pa + base;
    float rx[16], ry[16], rz[16];
    #pragma unroll
    for (int r = 0; r < 16; ++r) {
        rx[r] = rp[3 * r + 0];
        ry[r] = rp[3 * r + 1];
        rz[r] = rp[3 * r + 2];
    }
    float acc[16];
    #pragma unroll
    for (int r = 0; r < 16; ++r) acc[r] = 3.4e38f;

    #pragma unroll 2
    for (int t = 0; t < M_ / 64; ++t) {
        int ib = b * M_ + t * 64 + lane;
        float bx = pb[ib * 3 + 0], by = pb[ib * 3 + 1], bz = pb[ib * 3 + 2];
        float n2 = fmaf(bx, bx, fmaf(by, by, bz * bz));
        float qw = (wb[ib] != 0) ? n2 : BIG2;
        float qx = -2.0f * bx, qy = -2.0f * by, qz = -2.0f * bz;
        #pragma unroll
        for (int r = 0; r < 16; ++r) {
            float d = fmaf(rx[r], qx, fmaf(ry[r], qy, fmaf(rz[r], qz, qw)));
            acc[r] = fminf(acc[r], d);
        }
    }
    #pragma unroll
    for (int r = 0; r < 16; ++r) {
        float v = acc[r];
        #pragma unroll
        for (int off = 32; off; off >>= 1) v = fminf(v, __shfl_xor(v, off, 64));
        acc[r] = v;
    }
    int mbase = __builtin_amdgcn_readfirstlane(b * N_ + row0);
    const int* wp = wa + mbase;
    float sum = 0.0f;
    #pragma unroll
    for (int r = 0; r < 16; ++r) {
        float a2 = fmaf(rx[r], rx[r], fmaf(ry[r], ry[r], rz[r] * rz[r]));
        float d2 = fmaxf(a2 + acc[r], 0.0f);
        sum += (wp[r] != 0) ? d2 : 0.0f;
    }
    if (lane == 0) atomicAdd(&loss[b], 0.5f * sum);
}

extern "C" void kernel_launch(void* const* d_in, const int* in_sizes, int n_in,
                              void* d_out, int out_size, void* d_ws, size_t ws_size,
                              hipStream_t stream) {
    const int*   o_w   = (const int*)  d_in[0];
    const float* o_pts = (const float*)d_in[1];
    const int*   t_w   = (const int*)  d_in[2];
    const float* t_pts = (const float*)d_in[3];
    float* loss = (float*)d_out;

    const size_t part_bytes = (size_t)REP_ * B_ * 2 * GX_ * sizeof(float); // 16 KB

    if (ws_size >= part_bytes) {
        float* partials = (float*)d_ws;
        dim3 grid(GX_, B_, 2);                                        // (32, 32, 2)
        chamfer_main<<<grid, 512, 0, stream>>>(
            o_w, o_pts, t_w, t_pts, partials);
        chamfer_finish<<<1, 256, 0, stream>>>(partials, loss);
    } else {
        chamfer_zero<<<1, 64, 0, stream>>>(loss);
        dim3 grid(N_ / 64, B_, 2);
        chamfer_nolds<<<grid, 256, 0, stream>>>(
            o_w, o_pts, t_w, t_pts, loss);
    }
}

// Round 7
// 105.224 us; speedup vs baseline: 1.0093x; 1.0093x over previous
//
#include <hip/hip_runtime.h>

// Chamfer loss: B=32, N=M=2048, D=3.
// loss[b] = 0.5 * ( sum_n ma[n]*min_m d2(a_n,b_m) + sum_m mb[m]*min_n d2(b_m,a_n) )
// masked pairs -> BIG^2 = 1e16 (exact in fp32: |core| < ulp(1e16)).
//
// R12: fused one-pass REBUILT ON THE R11 SKELETON. R11's counters prove the
// kernel is VALU-issue-bound (29.7us/rep = 92% of the 27.3us instruction
// floor; occupancy 51%, conflicts 0, fetch tiny). Fusion computes the d2
// matrix once and feeds BOTH axis-mins: 6 instr / 2 elements (1 pk_add
// a2-fold + 3 pk_fma + 1 v_min3 row + 1 pk_min col) vs 8 for two-pass.
// Anti-balloon measures vs R6/R7 (128 VGPR + 150MB scratch): scalar racc,
// SGPR row constants + readfirstlane'd ca2, NO prefetch regs/unions/
// conditionals in the unrolled loop, named c0..c15, sched_barrier(0)
// every 4 tiles to cap hoisted ds_read pressure. Math bitwise-proven
// (R6/R7/R9 passed absmax 0.0; a2-fold exact by fmin monotonicity).
#define B_    32
#define N_    2048
#define M_    2048
#define RW_   8        // rows per wave
#define GX_   32       // row chunks per b: 2048 / (8 waves * 8 rows)
#define BIG2  1.0e16f
#define FINF  3.4e38f

typedef float v2f __attribute__((ext_vector_type(2)));

__device__ __forceinline__ v2f v2_fma(v2f a, v2f b, v2f c) {
#if __has_builtin(__builtin_elementwise_fma)
    return __builtin_elementwise_fma(a, b, c);
#else
    v2f r; r.x = fmaf(a.x, b.x, c.x); r.y = fmaf(a.y, b.y, c.y); return r;
#endif
}
__device__ __forceinline__ v2f v2_min(v2f a, v2f b) {
#if __has_builtin(__builtin_elementwise_min)
    return __builtin_elementwise_min(a, b);
#else
    v2f r; r.x = fminf(a.x, b.x); r.y = fminf(a.y, b.y); return r;
#endif
}
__device__ __forceinline__ v2f v2_splat(float s) { return (v2f){ s, s }; }
__device__ __forceinline__ float sgpr_f32(float v) {
    return __uint_as_float(__builtin_amdgcn_readfirstlane(__float_as_uint(v)));
}

// Fused main: grid (GX_, B_), 512 threads (8 waves). Wave wv owns rows
// [chunk*64 + wv*8, +8) of the OUTPUT side (constants in SGPRs). TARGET
// side staged in LDS as point-PAIR SoA:
//   sqA[p] = {-2x_{2p}, -2x_{2p+1}, -2y_{2p}, -2y_{2p+1}}
//   sqB[p] = {-2z_{2p}, -2z_{2p+1},  w_{2p},   w_{2p+1}}  (w = mask?|p|^2:1e16)
// Tile = 64 lanes x 2 points; per tile per row: pk_add (fold ca2) +
// 3 pk_fma + v_min3 (row acc, scalar) + pk_min (col acc).
__global__ __launch_bounds__(512) void chamfer_fused(
    const int* __restrict__ o_w, const float* __restrict__ o_pts,
    const int* __restrict__ t_w, const float* __restrict__ t_pts,
    float* __restrict__ rowpart,      // [B_][GX_]
    float* __restrict__ colpart)      // [B_][GX_][M_]
{
    const int chunk = blockIdx.x;
    const int b     = blockIdx.y;
    const int tid   = threadIdx.x;
    const int lane  = tid & 63;
    const int wv    = tid >> 6;
    const int row0  = chunk * (8 * RW_) + wv * RW_;

    __shared__ float4 sq[2048];        // 32 KB: sqA = sq[0:1024), sqB = sq[1024:2048)
    __shared__ float  wsum[8];
    float4* sqA = sq;
    float4* sqB = sq + 1024;
    float*  colbuf = (float*)sq;       // reused as [4][2048] after the inner loop

    // ---- Stage target slice: 512 threads x 2 pair-slots, coalesced float2.
    {
        const float2* src2 = (const float2*)(t_pts + (size_t)b * M_ * 3);
        const int2*   wb2  = (const int2*)(t_w + (size_t)b * M_);
        #pragma unroll
        for (int k = 0; k < 2; ++k) {
            int p = tid + k * 512;                 // pair index 0..1023
            float2 u0 = src2[p * 3 + 0];
            float2 u1 = src2[p * 3 + 1];
            float2 u2 = src2[p * 3 + 2];
            int2   mm = wb2[p];
            float x0 = u0.x, y0 = u0.y, z0 = u1.x;
            float x1 = u1.y, y1 = u2.x, z1 = u2.y;
            float n20 = fmaf(x0, x0, fmaf(y0, y0, z0 * z0));
            float n21 = fmaf(x1, x1, fmaf(y1, y1, z1 * z1));
            sqA[p] = make_float4(-2.f * x0, -2.f * x1, -2.f * y0, -2.f * y1);
            sqB[p] = make_float4(-2.f * z0, -2.f * z1,
                                 mm.x ? n20 : BIG2, mm.y ? n21 : BIG2);
        }
    }

    // ---- Row constants: wave-uniform base -> s_loads; ca2 forced to SGPR.
    int base  = __builtin_amdgcn_readfirstlane((b * N_ + row0) * 3);
    int mbase = __builtin_amdgcn_readfirstlane(b * N_ + row0);
    const float* rp = o_pts + base;
    const int*   wp = o_w + mbase;
    float rx[RW_], ry[RW_], rz[RW_], ca2[RW_];
    int   msk[RW_];
    #pragma unroll
    for (int r = 0; r < RW_; ++r) {
        rx[r] = rp[3 * r + 0];
        ry[r] = rp[3 * r + 1];
        rz[r] = rp[3 * r + 2];
        msk[r] = wp[r];
        float a2 = fmaf(rx[r], rx[r], fmaf(ry[r], ry[r], rz[r] * rz[r]));
        ca2[r] = sgpr_f32(msk[r] ? a2 : BIG2);  // masked row -> BIG2 in col-mins
    }
    __syncthreads();

    float racc[RW_];
    #pragma unroll
    for (int r = 0; r < RW_; ++r) racc[r] = FINF;

    // 16 NAMED column-min accumulators (compile-time indices -> VGPRs).
    v2f c0  = v2_splat(FINF), c1  = v2_splat(FINF), c2  = v2_splat(FINF), c3  = v2_splat(FINF);
    v2f c4  = v2_splat(FINF), c5  = v2_splat(FINF), c6  = v2_splat(FINF), c7  = v2_splat(FINF);
    v2f c8  = v2_splat(FINF), c9  = v2_splat(FINF), c10 = v2_splat(FINF), c11 = v2_splat(FINF);
    v2f c12 = v2_splat(FINF), c13 = v2_splat(FINF), c14 = v2_splat(FINF), c15 = v2_splat(FINF);

    // ---- Inner loop: 16 tiles of 128 points, macro-unrolled, no prefetch
    // regs; sched_barrier every 4 tiles caps hoisted-load VGPR pressure.
#define TILE(T, CT)                                                        \
    {                                                                      \
        float4 A  = sqA[(T) * 64 + lane];                                  \
        float4 Bq = sqB[(T) * 64 + lane];                                  \
        v2f xs = (v2f){ A.x,  A.y  };                                      \
        v2f ys = (v2f){ A.z,  A.w  };                                      \
        v2f zs = (v2f){ Bq.x, Bq.y };                                      \
        v2f ws = (v2f){ Bq.z, Bq.w };                                      \
        _Pragma("unroll")                                                  \
        for (int r = 0; r < RW_; ++r) {                                    \
            v2f wr = ws + v2_splat(ca2[r]);                                \
            v2f d  = v2_fma(v2_splat(rx[r]), xs,                           \
                     v2_fma(v2_splat(ry[r]), ys,                           \
                     v2_fma(v2_splat(rz[r]), zs, wr)));                    \
            racc[r] = fminf(fminf(d.x, d.y), racc[r]);  /* v_min3 */       \
            CT      = v2_min(CT, d);                                       \
        }                                                                  \
    }

    TILE(0,  c0)  TILE(1,  c1)  TILE(2,  c2)  TILE(3,  c3)
    __builtin_amdgcn_sched_barrier(0);
    TILE(4,  c4)  TILE(5,  c5)  TILE(6,  c6)  TILE(7,  c7)
    __builtin_amdgcn_sched_barrier(0);
    TILE(8,  c8)  TILE(9,  c9)  TILE(10, c10) TILE(11, c11)
    __builtin_amdgcn_sched_barrier(0);
    TILE(12, c12) TILE(13, c13) TILE(14, c14) TILE(15, c15)
#undef TILE

    // ---- Row side: cross-lane min per row + masked sum. racc already
    // includes a2 (fold exact: fl monotone -> min(a2+u) == a2+min(u)).
    float sum = 0.0f;
    #pragma unroll
    for (int r = 0; r < RW_; ++r) {
        float m = racc[r];
        #pragma unroll
        for (int off = 32; off; off >>= 1)
            m = fminf(m, __shfl_xor(m, off, 64));
        sum += msk[r] ? fmaxf(m, 0.0f) : 0.0f;
    }
    if (lane == 0) wsum[wv] = sum;

    __syncthreads();   // all waves done reading sq; wsum visible

#define FOR_ALL_C(F)                                                       \
    F(0,  c0)  F(1,  c1)  F(2,  c2)  F(3,  c3)                             \
    F(4,  c4)  F(5,  c5)  F(6,  c6)  F(7,  c7)                             \
    F(8,  c8)  F(9,  c9)  F(10, c10) F(11, c11)                            \
    F(12, c12) F(13, c13) F(14, c14) F(15, c15)

    // ---- Col side: 8-wave tree min reusing the stage LDS as colbuf[4][2048].
    // Round A: waves 4..7 deposit their accumulators.
    if (wv >= 4) {
#define PUTC(T, CT) *(v2f*)&colbuf[(wv - 4) * 2048 + (T) * 128 + 2 * lane] = CT;
        FOR_ALL_C(PUTC)
#undef PUTC
    }
    __syncthreads();
    // Round B: waves 0..3 fold theirs in. tid 0 emits the row partial.
    if (wv < 4) {
#define FOLDC(T, CT)                                                       \
        {                                                                  \
            v2f* p = (v2f*)&colbuf[wv * 2048 + (T) * 128 + 2 * lane];      \
            *p = v2_min(*p, CT);                                           \
        }
        FOR_ALL_C(FOLDC)
#undef FOLDC
    }
    if (tid == 0) {
        float s = 0.f;
        #pragma unroll
        for (int i = 0; i < 8; ++i) s += wsum[i];
        rowpart[b * GX_ + chunk] = s;
    }
    __syncthreads();
    // Round C: 4 arrays -> 2.
    if (wv < 2) {
        #pragma unroll
        for (int t = 0; t < 16; ++t) {
            int c = t * 128 + 2 * lane;
            v2f a  = *(v2f*)&colbuf[wv * 2048 + c];
            v2f bb = *(v2f*)&colbuf[(wv + 2) * 2048 + c];
            *(v2f*)&colbuf[wv * 2048 + c] = v2_min(a, bb);
        }
    }
    __syncthreads();
    // Round D: 2 -> 1 and coalesced float4 store of the block's col partials.
    {
        float4 a  = *(float4*)&colbuf[0 * 2048 + tid * 4];
        float4 bb = *(float4*)&colbuf[1 * 2048 + tid * 4];
        float4 mn;
        mn.x = fminf(a.x, bb.x);
        mn.y = fminf(a.y, bb.y);
        mn.z = fminf(a.z, bb.z);
        mn.w = fminf(a.w, bb.w);
        *(float4*)&colpart[((size_t)b * GX_ + chunk) * M_ + tid * 4] = mn;
    }
#undef FOR_ALL_C
}

// Finish: 32 blocks (one per b), 512 threads. Thread t owns 4 cols: min over
// the 32 chunk partials (coalesced float4, stride 8 KB), clamp+mask+sum, add
// the 32 row partials, block-reduce, one store.
__global__ __launch_bounds__(512) void chamfer_finish2(
    const float* __restrict__ rowpart, const float* __restrict__ colpart,
    const int* __restrict__ t_w, float* __restrict__ loss)
{
    const int b = blockIdx.x, tid = threadIdx.x;
    const int lane = tid & 63, wv = tid >> 6;
    const float4* cp = (const float4*)(colpart + (size_t)b * GX_ * M_);
    float4 mn = cp[tid];
    #pragma unroll 8
    for (int k = 1; k < GX_; ++k) {
        float4 v = cp[k * 512 + tid];
        mn.x = fminf(mn.x, v.x);
        mn.y = fminf(mn.y, v.y);
        mn.z = fminf(mn.z, v.z);
        mn.w = fminf(mn.w, v.w);
    }
    int4 mm = ((const int4*)(t_w + (size_t)b * M_))[tid];
    float s = (mm.x ? fmaxf(mn.x, 0.f) : 0.f)
            + (mm.y ? fmaxf(mn.y, 0.f) : 0.f)
            + (mm.z ? fmaxf(mn.z, 0.f) : 0.f)
            + (mm.w ? fmaxf(mn.w, 0.f) : 0.f);
    if (tid < GX_) s += rowpart[b * GX_ + tid];
    #pragma unroll
    for (int off = 32; off; off >>= 1) s += __shfl_xor(s, off, 64);
    __shared__ float ws8[8];
    if (lane == 0) ws8[wv] = s;
    __syncthreads();
    if (tid == 0) {
        float tot = 0.f;
        #pragma unroll
        for (int i = 0; i < 8; ++i) tot += ws8[i];
        loss[b] = 0.5f * tot;
    }
}

// ---------- Fallback (ws too small): prep-on-the-fly + atomics ----------
__global__ void chamfer_zero(float* __restrict__ loss)
{
    if (threadIdx.x < B_) loss[threadIdx.x] = 0.0f;
}

__global__ __launch_bounds__(256) void chamfer_nolds(
    const int* __restrict__ o_w, const float* __restrict__ o_pts,
    const int* __restrict__ t_w, const float* __restrict__ t_pts,
    float* __restrict__ loss)
{
    const int dir  = blockIdx.z;
    const int b    = blockIdx.y;
    const int lane = threadIdx.x & 63;
    const int wv   = threadIdx.x >> 6;
    const int row0 = (blockIdx.x * 4 + wv) * 16;

    const int*   __restrict__ wa = (dir == 0) ? o_w   : t_w;
    const float* __restrict__ pa = (dir == 0) ? o_pts : t_pts;
    const int*   __restrict__ wb = (dir == 0) ? t_w   : o_w;
    const float* __restrict__ pb = (dir == 0) ? t_pts : o_pts;

    int base = __builtin_amdgcn_readfirstlane((b * N_ + row0) * 3);
    const float* rp = pa + base;
    float rx[16], ry[16], rz[16];
    #pragma unroll
    for (int r = 0; r < 16; ++r) {
        rx[r] = rp[3 * r + 0];
        ry[r] = rp[3 * r + 1];
        rz[r] = rp[3 * r + 2];
    }
    float acc[16];
    #pragma unroll
    for (int r = 0; r < 16; ++r) acc[r] = 3.4e38f;

    #pragma unroll 2
    for (int t = 0; t < M_ / 64; ++t) {
        int ib = b * M_ + t * 64 + lane;
        float bx = pb[ib * 3 + 0], by = pb[ib * 3 + 1], bz = pb[ib * 3 + 2];
        float n2 = fmaf(bx, bx, fmaf(by, by, bz * bz));
        float qw = (wb[ib] != 0) ? n2 : BIG2;
        float qx = -2.0f * bx, qy = -2.0f * by, qz = -2.0f * bz;
        #pragma unroll
        for (int r = 0; r < 16; ++r) {
            float d = fmaf(rx[r], qx, fmaf(ry[r], qy, fmaf(rz[r], qz, qw)));
            acc[r] = fminf(acc[r], d);
        }
    }
    #pragma unroll
    for (int r = 0; r < 16; ++r) {
        float v = acc[r];
        #pragma unroll
        for (int off = 32; off; off >>= 1) v = fminf(v, __shfl_xor(v, off, 64));
        acc[r] = v;
    }
    int mbase = __builtin_amdgcn_readfirstlane(b * N_ + row0);
    const int* wp = wa + mbase;
    float sum = 0.0f;
    #pragma unroll
    for (int r = 0; r < 16; ++r) {
        float a2 = fmaf(rx[r], rx[r], fmaf(ry[r], ry[r], rz[r] * rz[r]));
        float d2 = fmaxf(a2 + acc[r], 0.0f);
        sum += (wp[r] != 0) ? d2 : 0.0f;
    }
    if (lane == 0) atomicAdd(&loss[b], 0.5f * sum);
}

extern "C" void kernel_launch(void* const* d_in, const int* in_sizes, int n_in,
                              void* d_out, int out_size, void* d_ws, size_t ws_size,
                              hipStream_t stream) {
    const int*   o_w   = (const int*)  d_in[0];
    const float* o_pts = (const float*)d_in[1];
    const int*   t_w   = (const int*)  d_in[2];
    const float* t_pts = (const float*)d_in[3];
    float* loss = (float*)d_out;

    const size_t row_bytes = (size_t)B_ * GX_ * sizeof(float);        // 4 KB
    const size_t col_bytes = (size_t)B_ * GX_ * M_ * sizeof(float);   // 8 MB

    if (ws_size >= row_bytes + col_bytes) {
        float* rowpart = (float*)d_ws;                 // [B][GX]
        float* colpart = (float*)d_ws + B_ * GX_;      // [B][GX][M], 16B-aligned
        dim3 grid(GX_, B_);                            // (32, 32)
        chamfer_fused<<<grid, 512, 0, stream>>>(
            o_w, o_pts, t_w, t_pts, rowpart, colpart);
        chamfer_finish2<<<B_, 512, 0, stream>>>(rowpart, colpart, t_w, loss);
    } else {
        chamfer_zero<<<1, 64, 0, stream>>>(loss);
        dim3 grid(N_ / 64, B_, 2);
        chamfer_nolds<<<grid, 256, 0, stream>>>(
            o_w, o_pts, t_w, t_pts, loss);
    }
}

// Round 8
// 85.990 us; speedup vs baseline: 1.2351x; 1.2237x over previous
//
#include <hip/hip_runtime.h>

// Chamfer loss: B=32, N=M=2048, D=3.
// loss[b] = 0.5 * ( sum_n ma[n]*min_m d2(a_n,b_m) + sum_m mb[m]*min_n d2(b_m,a_n) )
// masked pairs -> BIG^2 = 1e16 (exact in fp32 vs BIG=1e8 reference).
//
// R13: fused one-pass with O(1) COLUMN STATE. R6/R7/R12 all ballooned to
// 128 VGPR + scratch because 16 v2f column accumulators live across a
// 16-tile unroll defeat the allocator. Fix: block-wide col-mins live in
// LDS (colmin[2048], 8 KB); each wave folds a 2-VGPR per-tile pk-min into
// it via plain read-min-write. Race-free by CHECKERBOARD ROTATION: at step
// s, wave wv owns tile (s + 2*wv) & 15 -> 8 disjoint 128-col ranges;
// __syncthreads() per step rotates ownership. fmin is exactly associative
// -> bitwise-deterministic. Live set ~40 VGPR = R11's proven regime
// (36 VGPR, 92% of VALU floor). Inner: 6 instr / 2 matrix elements
// (pk_add a2-fold + 3 pk_fma + v_min3 row + pk_min col) vs 8 for
// two-pass. 512 blocks (2 chunks of 64 rows each), 2 resident/CU.
#define B_    32
#define N_    2048
#define M_    2048
#define RW_   8        // rows per wave
#define CB_   16       // chunk-blocks per b (each covers 128 rows)
#define BIG2  1.0e16f
#define FINF  3.4e38f

typedef float v2f __attribute__((ext_vector_type(2)));

__device__ __forceinline__ v2f v2_fma(v2f a, v2f b, v2f c) {
#if __has_builtin(__builtin_elementwise_fma)
    return __builtin_elementwise_fma(a, b, c);
#else
    v2f r; r.x = fmaf(a.x, b.x, c.x); r.y = fmaf(a.y, b.y, c.y); return r;
#endif
}
__device__ __forceinline__ v2f v2_min(v2f a, v2f b) {
#if __has_builtin(__builtin_elementwise_min)
    return __builtin_elementwise_min(a, b);
#else
    v2f r; r.x = fminf(a.x, b.x); r.y = fminf(a.y, b.y); return r;
#endif
}
__device__ __forceinline__ v2f v2_splat(float s) { return (v2f){ s, s }; }
__device__ __forceinline__ float sgpr_f32(float v) {
    return __uint_as_float(__builtin_amdgcn_readfirstlane(__float_as_uint(v)));
}

// Fused main: grid (CB_, B_), 512 threads (8 waves). Block bx covers rows
// [bx*128, +128) as 2 chunks of 64 (wave wv owns 8 rows per chunk).
// TARGET side staged once in LDS as point-PAIR SoA:
//   sqA[p] = {-2x_{2p}, -2x_{2p+1}, -2y_{2p}, -2y_{2p+1}}
//   sqB[p] = {-2z_{2p}, -2z_{2p+1},  w_{2p},   w_{2p+1}}  (w = mask?|p|^2:1e16)
// Per step per row: pk_add (fold ca2) + 3 pk_fma + v_min3 (row) ;
// per step: pk_min chain into cm (2 VGPR) then LDS read-min-write.
__global__ __launch_bounds__(512) void chamfer_fused(
    const int* __restrict__ o_w, const float* __restrict__ o_pts,
    const int* __restrict__ t_w, const float* __restrict__ t_pts,
    float* __restrict__ rowpart,      // [B_][CB_]
    float* __restrict__ colpart)      // [B_][CB_][M_]
{
    const int bx   = blockIdx.x;
    const int b    = blockIdx.y;
    const int tid  = threadIdx.x;
    const int lane = tid & 63;
    const int wv   = tid >> 6;

    __shared__ float4 sq[2048];            // 32 KB (sqA | sqB)
    __shared__ __align__(16) float colmin[M_];  // 8 KB block-wide col mins
    __shared__ float wsum[8];
    float4* sqA = sq;
    float4* sqB = sq + 1024;

    // ---- Stage target slice: 512 threads x 2 pair-slots, coalesced float2.
    {
        const float2* src2 = (const float2*)(t_pts + (size_t)b * M_ * 3);
        const int2*   wb2  = (const int2*)(t_w + (size_t)b * M_);
        #pragma unroll
        for (int k = 0; k < 2; ++k) {
            int p = tid + k * 512;                 // pair index 0..1023
            float2 u0 = src2[p * 3 + 0];
            float2 u1 = src2[p * 3 + 1];
            float2 u2 = src2[p * 3 + 2];
            int2   mm = wb2[p];
            float x0 = u0.x, y0 = u0.y, z0 = u1.x;
            float x1 = u1.y, y1 = u2.x, z1 = u2.y;
            float n20 = fmaf(x0, x0, fmaf(y0, y0, z0 * z0));
            float n21 = fmaf(x1, x1, fmaf(y1, y1, z1 * z1));
            sqA[p] = make_float4(-2.f * x0, -2.f * x1, -2.f * y0, -2.f * y1);
            sqB[p] = make_float4(-2.f * z0, -2.f * z1,
                                 mm.x ? n20 : BIG2, mm.y ? n21 : BIG2);
        }
        #pragma unroll
        for (int k = 0; k < 4; ++k) colmin[tid + k * 512] = FINF;
    }
    __syncthreads();

    float sum = 0.0f;   // row-side partial (accumulates across both chunks)

    #pragma unroll 1
    for (int c = 0; c < 2; ++c) {
        const int row0 = bx * 128 + c * 64 + wv * RW_;

        // Row constants: wave-uniform base -> scalar loads; ca2 -> SGPR.
        int base  = __builtin_amdgcn_readfirstlane((b * N_ + row0) * 3);
        int mbase = __builtin_amdgcn_readfirstlane(b * N_ + row0);
        const float* rp = o_pts + base;
        const int*   wp = o_w + mbase;
        float rx[RW_], ry[RW_], rz[RW_], ca2[RW_];
        int   msk[RW_];
        #pragma unroll
        for (int r = 0; r < RW_; ++r) {
            rx[r] = rp[3 * r + 0];
            ry[r] = rp[3 * r + 1];
            rz[r] = rp[3 * r + 2];
            msk[r] = wp[r];
            float a2 = fmaf(rx[r], rx[r], fmaf(ry[r], ry[r], rz[r] * rz[r]));
            ca2[r] = sgpr_f32(msk[r] ? a2 : BIG2);
        }

        float racc[RW_];
        #pragma unroll
        for (int r = 0; r < RW_; ++r) racc[r] = FINF;

        // ---- 16 steps; wave wv owns tile (s + 2*wv) & 15 at step s.
        #pragma unroll 1
        for (int s = 0; s < 16; ++s) {
            const int t = (s + 2 * wv) & 15;
            float4 A  = sqA[t * 64 + lane];
            float4 Bq = sqB[t * 64 + lane];
            v2f xs = (v2f){ A.x,  A.y  };
            v2f ys = (v2f){ A.z,  A.w  };
            v2f zs = (v2f){ Bq.x, Bq.y };
            v2f ws = (v2f){ Bq.z, Bq.w };
            v2f cm = v2_splat(FINF);
            #pragma unroll
            for (int r = 0; r < RW_; ++r) {
                v2f wr = ws + v2_splat(ca2[r]);
                v2f d  = v2_fma(v2_splat(rx[r]), xs,
                         v2_fma(v2_splat(ry[r]), ys,
                         v2_fma(v2_splat(rz[r]), zs, wr)));
                racc[r] = fminf(fminf(d.x, d.y), racc[r]);   // v_min3
                cm      = v2_min(cm, d);
            }
            // Exclusive read-min-write into this wave's 128-col range.
            v2f* cp = (v2f*)&colmin[t * 128 + 2 * lane];
            *cp = v2_min(*cp, cm);
            __syncthreads();   // rotate ownership (lgkmcnt drained by sync)
        }

        // ---- Row epilogue for this chunk (registers + shfl only).
        #pragma unroll
        for (int r = 0; r < RW_; ++r) {
            float m = racc[r];
            #pragma unroll
            for (int off = 32; off; off >>= 1)
                m = fminf(m, __shfl_xor(m, off, 64));
            sum += msk[r] ? fmaxf(m, 0.0f) : 0.0f;
        }
    }

    // ---- Block reduce row side; dump colmin to global.
    if (lane == 0) wsum[wv] = sum;
    __syncthreads();
    if (tid == 0) {
        float s8 = 0.f;
        #pragma unroll
        for (int i = 0; i < 8; ++i) s8 += wsum[i];
        rowpart[b * CB_ + bx] = s8;
    }
    {
        float4* dst = (float4*)&colpart[((size_t)b * CB_ + bx) * M_];
        dst[tid] = *(float4*)&colmin[tid * 4];
    }
}

// Finish: 32 blocks (one per b), 512 threads. Thread t owns 4 cols: min
// over the 16 chunk-block partials (coalesced float4, stride 8 KB),
// mask+clamp+sum, add the 16 row partials, block-reduce, one store.
__global__ __launch_bounds__(512) void chamfer_finish2(
    const float* __restrict__ rowpart, const float* __restrict__ colpart,
    const int* __restrict__ t_w, float* __restrict__ loss)
{
    const int b = blockIdx.x, tid = threadIdx.x;
    const int lane = tid & 63, wv = tid >> 6;
    const float4* cp = (const float4*)(colpart + (size_t)b * CB_ * M_);
    float4 mn = cp[tid];
    #pragma unroll
    for (int k = 1; k < CB_; ++k) {
        float4 v = cp[k * 512 + tid];
        mn.x = fminf(mn.x, v.x);
        mn.y = fminf(mn.y, v.y);
        mn.z = fminf(mn.z, v.z);
        mn.w = fminf(mn.w, v.w);
    }
    int4 mm = ((const int4*)(t_w + (size_t)b * M_))[tid];
    float s = (mm.x ? fmaxf(mn.x, 0.f) : 0.f)
            + (mm.y ? fmaxf(mn.y, 0.f) : 0.f)
            + (mm.z ? fmaxf(mn.z, 0.f) : 0.f)
            + (mm.w ? fmaxf(mn.w, 0.f) : 0.f);
    if (tid < CB_) s += rowpart[b * CB_ + tid];
    #pragma unroll
    for (int off = 32; off; off >>= 1) s += __shfl_xor(s, off, 64);
    __shared__ float ws8[8];
    if (lane == 0) ws8[wv] = s;
    __syncthreads();
    if (tid == 0) {
        float tot = 0.f;
        #pragma unroll
        for (int i = 0; i < 8; ++i) tot += ws8[i];
        loss[b] = 0.5f * tot;
    }
}

// ---------- Fallback (ws too small): prep-on-the-fly + atomics ----------
__global__ void chamfer_zero(float* __restrict__ loss)
{
    if (threadIdx.x < B_) loss[threadIdx.x] = 0.0f;
}

__global__ __launch_bounds__(256) void chamfer_nolds(
    const int* __restrict__ o_w, const float* __restrict__ o_pts,
    const int* __restrict__ t_w, const float* __restrict__ t_pts,
    float* __restrict__ loss)
{
    const int dir  = blockIdx.z;
    const int b    = blockIdx.y;
    const int lane = threadIdx.x & 63;
    const int wv   = threadIdx.x >> 6;
    const int row0 = (blockIdx.x * 4 + wv) * 16;

    const int*   __restrict__ wa = (dir == 0) ? o_w   : t_w;
    const float* __restrict__ pa = (dir == 0) ? o_pts : t_pts;
    const int*   __restrict__ wb = (dir == 0) ? t_w   : o_w;
    const float* __restrict__ pb = (dir == 0) ? t_pts : o_pts;

    int base = __builtin_amdgcn_readfirstlane((b * N_ + row0) * 3);
    const float* rp = pa + base;
    float rx[16], ry[16], rz[16];
    #pragma unroll
    for (int r = 0; r < 16; ++r) {
        rx[r] = rp[3 * r + 0];
        ry[r] = rp[3 * r + 1];
        rz[r] = rp[3 * r + 2];
    }
    float acc[16];
    #pragma unroll
    for (int r = 0; r < 16; ++r) acc[r] = 3.4e38f;

    #pragma unroll 2
    for (int t = 0; t < M_ / 64; ++t) {
        int ib = b * M_ + t * 64 + lane;
        float bx = pb[ib * 3 + 0], by = pb[ib * 3 + 1], bz = pb[ib * 3 + 2];
        float n2 = fmaf(bx, bx, fmaf(by, by, bz * bz));
        float qw = (wb[ib] != 0) ? n2 : BIG2;
        float qx = -2.0f * bx, qy = -2.0f * by, qz = -2.0f * bz;
        #pragma unroll
        for (int r = 0; r < 16; ++r) {
            float d = fmaf(rx[r], qx, fmaf(ry[r], qy, fmaf(rz[r], qz, qw)));
            acc[r] = fminf(acc[r], d);
        }
    }
    #pragma unroll
    for (int r = 0; r < 16; ++r) {
        float v = acc[r];
        #pragma unroll
        for (int off = 32; off; off >>= 1) v = fminf(v, __shfl_xor(v, off, 64));
        acc[r] = v;
    }
    int mbase = __builtin_amdgcn_readfirstlane(b * N_ + row0);
    const int* wp = wa + mbase;
    float sum = 0.0f;
    #pragma unroll
    for (int r = 0; r < 16; ++r) {
        float a2 = fmaf(rx[r], rx[r], fmaf(ry[r], ry[r], rz[r] * rz[r]));
        float d2 = fmaxf(a2 + acc[r], 0.0f);
        sum += (wp[r] != 0) ? d2 : 0.0f;
    }
    if (lane == 0) atomicAdd(&loss[b], 0.5f * sum);
}

extern "C" void kernel_launch(void* const* d_in, const int* in_sizes, int n_in,
                              void* d_out, int out_size, void* d_ws, size_t ws_size,
                              hipStream_t stream) {
    const int*   o_w   = (const int*)  d_in[0];
    const float* o_pts = (const float*)d_in[1];
    const int*   t_w   = (const int*)  d_in[2];
    const float* t_pts = (const float*)d_in[3];
    float* loss = (float*)d_out;

    const size_t row_bytes = (size_t)B_ * CB_ * sizeof(float);        // 2 KB
    const size_t col_bytes = (size_t)B_ * CB_ * M_ * sizeof(float);   // 4 MB

    if (ws_size >= row_bytes + col_bytes) {
        float* rowpart = (float*)d_ws;                 // [B][CB]
        float* colpart = (float*)d_ws + B_ * CB_;      // [B][CB][M], 16B-aligned
        dim3 grid(CB_, B_);                            // (16, 32) = 512 blocks
        chamfer_fused<<<grid, 512, 0, stream>>>(
            o_w, o_pts, t_w, t_pts, rowpart, colpart);
        chamfer_finish2<<<B_, 512, 0, stream>>>(rowpart, colpart, t_w, loss);
    } else {
        chamfer_zero<<<1, 64, 0, stream>>>(loss);
        dim3 grid(N_ / 64, B_, 2);
        chamfer_nolds<<<grid, 256, 0, stream>>>(
            o_w, o_pts, t_w, t_pts, loss);
    }
}